// Round 5
// baseline (197.288 us; speedup 1.0000x reference)
//
#include <hip/hip_runtime.h>
#include <math.h>

// ---------------------------------------------------------------------------
// TemporalGuidedModule round 5:
//  - gemm3_k: 128p x 256o tile (X read ONCE), BK=64, 512 thr / 8 waves,
//    96KB dbuf LDS + XOR swizzle, grid = 256 blocks = 1/CU.
//  - gemm2_k retained only for the Cout=192 offs+attn GEMM (pm f32 out).
//  - msda: VGPR diet (per-point float2 offsets, unroll 2, launch_bounds(256,4)).
// ---------------------------------------------------------------------------

#define PIX 16384
#define BATCH 2
#define CH 256

typedef short bf16x8 __attribute__((ext_vector_type(8)));
typedef float f32x4 __attribute__((ext_vector_type(4)));

__device__ __forceinline__ ushort f2bf(float f) {
  union { float f; unsigned u; } v; v.f = f;
  unsigned u = v.u;
  unsigned r = u + 0x7fffu + ((u >> 16) & 1u);   // RNE
  return (ushort)(r >> 16);
}
__device__ __forceinline__ float bfl(unsigned u) {
  union { unsigned u; float f; } v; v.u = u << 16; return v.f;
}
__device__ __forceinline__ float bfh(unsigned u) {
  union { unsigned u; float f; } v; v.u = u & 0xffff0000u; return v.f;
}
__device__ __forceinline__ unsigned fuse_u32(unsigned a, unsigned b, bool mul) {
  float rl = mul ? bfl(a) * bfl(b) : bfl(a) + bfl(b);
  float rh = mul ? bfh(a) * bfh(b) : bfh(a) + bfh(b);
  return (unsigned)f2bf(rl) | ((unsigned)f2bf(rh) << 16);
}

// --------------------------------------------------------------------------
// Weight prep + bias concat (as r4).
// --------------------------------------------------------------------------
__global__ __launch_bounds__(256) void wprep_k(
    const float* __restrict__ W_in1, const float* __restrict__ Wo,
    const float* __restrict__ Wt1, const float* __restrict__ Wt2,
    const float* __restrict__ Wout, const float* __restrict__ Ws,
    const float* __restrict__ Wa, const float* __restrict__ bs_off,
    const float* __restrict__ ba, ushort* __restrict__ wb,
    float* __restrict__ bsa)
{
  const int blk = blockIdx.x, k = threadIdx.x;
  if (blk >= 1472) {
    if (k < 128) bsa[k] = bs_off[k];
    else if (k < 192) bsa[k] = ba[k - 128];
    return;
  }
  const float* src;
  if (blk < 256) src = W_in1 + (size_t)blk * 256;
  else if (blk < 512) src = Wo + (size_t)(blk - 256) * 256;
  else if (blk < 768) src = Wt1 + (size_t)(blk - 512) * 256;
  else if (blk < 1024) src = Wt2 + (size_t)(blk - 768) * 256;
  else if (blk < 1280) src = Wout + (size_t)(blk - 1024) * 256;
  else if (blk < 1408) src = Ws + (size_t)(blk - 1280) * 256;
  else src = Wa + (size_t)(blk - 1408) * 256;
  wb[(size_t)blk * 256 + k] = f2bf(src[k]);
}

// Wv' = Wv @ W_in2 (bf16), bv' = Wv @ b_in2 + bv.
__global__ __launch_bounds__(256) void wvcomp_k(
    const float* __restrict__ Wv, const float* __restrict__ W_in2,
    const float* __restrict__ b_in2, const float* __restrict__ bv,
    ushort* __restrict__ Wvp, float* __restrict__ bvp)
{
  const int o = blockIdx.x, k = threadIdx.x;
  float acc = 0.f;
  #pragma unroll 8
  for (int c = 0; c < 256; ++c)
    acc += Wv[(size_t)o * 256 + c] * W_in2[(size_t)c * 256 + k];
  Wvp[(size_t)o * 256 + k] = f2bf(acc);
  __shared__ float red[256];
  red[k] = Wv[(size_t)o * 256 + k] * b_in2[k];
  __syncthreads();
  for (int s = 128; s > 0; s >>= 1) {
    if (k < s) red[k] += red[k + s];
    __syncthreads();
  }
  if (k == 0) bvp[o] = red[0] + bv[o];
}

// --------------------------------------------------------------------------
// Transpose-convert: [B][C][P] f32 -> [B][P][C] bf16.
// --------------------------------------------------------------------------
__global__ __launch_bounds__(256) void tconv_k(const float* __restrict__ in,
                                               ushort* __restrict__ out)
{
  __shared__ float t[32][33];
  const int tid = threadIdx.x;
  const int b = blockIdx.z;
  const int p0 = blockIdx.x * 32, c0 = blockIdx.y * 32;
  const int tx = tid & 31, ty = tid >> 5;
  const float* inb = in + (size_t)b * CH * PIX;
  #pragma unroll
  for (int i = 0; i < 4; ++i)
    t[ty + i * 8][tx] = inb[(size_t)(c0 + ty + i * 8) * PIX + p0 + tx];
  __syncthreads();
  const int cx = (tid & 15) * 2, py = tid >> 4;
  ushort* outb = out + (size_t)b * PIX * CH;
  #pragma unroll
  for (int i = 0; i < 2; ++i) {
    int pl = py + i * 16;
    unsigned lo = f2bf(t[cx][pl]);
    unsigned hi = f2bf(t[cx + 1][pl]);
    *(unsigned*)(outb + (size_t)(p0 + pl) * CH + c0 + cx) = lo | (hi << 16);
  }
}

// --------------------------------------------------------------------------
// gemm3_k: Out[p][o] = sum_k X[p][k]*W[o][k] + bias[o], Cout = 256 fixed.
// Tile 128p x 256o, BK=64, 512 thr / 8 waves (2x4), wave tile 64x64.
// dbuf XOR-swizzled LDS: X at {0,16K} [128][64]h, W at 32K+{0,32K} [256][64]h.
// OMODE 0: pm bf16 out (LDS bounce [128][272]h); 1: cm f32 direct.
// FUSE 0 none; 1 x*=in2; 2 x+=in2 (in2 pm bf16).
// --------------------------------------------------------------------------
template<int FUSE, bool RELU, int OMODE>
__global__ __launch_bounds__(512, 2) void gemm3_k(
    const ushort* __restrict__ in, const ushort* __restrict__ in2,
    const ushort* __restrict__ Wb, const float* __restrict__ bias,
    void* __restrict__ out)
{
  __shared__ __align__(16) char smem[98304];
  const int tid = threadIdx.x;
  const int b = blockIdx.z;
  const int p0 = blockIdx.x * 128;

  const ushort* inb = in + (size_t)b * PIX * CH;

  // X staging: 4 thr/row, 32B each
  const int xrr = tid >> 2, xq = tid & 3;
  const ushort* xsrc = inb + (size_t)(p0 + xrr) * CH + xq * 16;
  const ushort* x2src = (FUSE != 0)
      ? in2 + (size_t)b * PIX * CH + (size_t)(p0 + xrr) * CH + xq * 16
      : (const ushort*)nullptr;
  // W staging: 2 thr/row, 64B each
  const int wrr = tid >> 1, whq = tid & 1;
  const ushort* wsrc = Wb + (size_t)wrr * CH + whq * 32;

  const int l = tid & 63, wid = tid >> 6;
  const int wm = wid >> 2, wn = wid & 3;
  const int lr = l & 15, g4 = l >> 4;

  f32x4 acc[4][4];
  #pragma unroll
  for (int i = 0; i < 4; ++i)
    #pragma unroll
    for (int j = 0; j < 4; ++j) acc[i][j] = (f32x4){0.f, 0.f, 0.f, 0.f};

  uint4 xr[2], x2r[2], wr[4];

#define LOADT(kb)                                                              \
  {                                                                            \
    _Pragma("unroll")                                                          \
    for (int j = 0; j < 2; ++j) xr[j] = *(const uint4*)(xsrc + (kb) + j * 8);  \
    if (FUSE != 0) {                                                           \
      _Pragma("unroll")                                                        \
      for (int j = 0; j < 2; ++j) x2r[j] = *(const uint4*)(x2src + (kb) + j * 8); \
    }                                                                          \
    _Pragma("unroll")                                                          \
    for (int j = 0; j < 4; ++j) wr[j] = *(const uint4*)(wsrc + (kb) + j * 8);  \
  }

#define WRITET(buf)                                                            \
  {                                                                            \
    char* xb = smem + (buf) * 16384 + xrr * 128;                               \
    _Pragma("unroll")                                                          \
    for (int j = 0; j < 2; ++j) {                                              \
      uint4 v = xr[j];                                                         \
      if (FUSE != 0) {                                                         \
        unsigned* pa = (unsigned*)&v;                                          \
        const unsigned* pb = (const unsigned*)&x2r[j];                         \
        _Pragma("unroll")                                                      \
        for (int w = 0; w < 4; ++w) pa[w] = fuse_u32(pa[w], pb[w], FUSE == 1); \
      }                                                                        \
      *(uint4*)(xb + (((xq * 2 + j) ^ (xrr & 7)) * 16)) = v;                   \
    }                                                                          \
    char* wbp = smem + 32768 + (buf) * 32768 + wrr * 128;                      \
    _Pragma("unroll")                                                          \
    for (int j = 0; j < 4; ++j)                                                \
      *(uint4*)(wbp + (((whq * 4 + j) ^ (wrr & 7)) * 16)) = wr[j];             \
  }

  LOADT(0)
  WRITET(0)
  __syncthreads();

  for (int t = 0; t < 4; ++t) {
    if (t < 3) LOADT((t + 1) * 64)
    const char* XB = smem + (t & 1) * 16384;
    const char* WB = smem + 32768 + (t & 1) * 32768;
    bf16x8 af[4][2], bfr[4][2];
    #pragma unroll
    for (int fm = 0; fm < 4; ++fm) {
      const int p = wm * 64 + fm * 16 + lr;
      #pragma unroll
      for (int kh = 0; kh < 2; ++kh)
        af[fm][kh] = *(const bf16x8*)(XB + p * 128 + (((kh * 4 + g4) ^ (p & 7)) * 16));
    }
    #pragma unroll
    for (int fn = 0; fn < 4; ++fn) {
      const int o = wn * 64 + fn * 16 + lr;
      #pragma unroll
      for (int kh = 0; kh < 2; ++kh)
        bfr[fn][kh] = *(const bf16x8*)(WB + o * 128 + (((kh * 4 + g4) ^ (o & 7)) * 16));
    }
    #pragma unroll
    for (int fm = 0; fm < 4; ++fm)
      #pragma unroll
      for (int fn = 0; fn < 4; ++fn) {
        acc[fm][fn] = __builtin_amdgcn_mfma_f32_16x16x32_bf16(af[fm][0], bfr[fn][0], acc[fm][fn], 0, 0, 0);
        acc[fm][fn] = __builtin_amdgcn_mfma_f32_16x16x32_bf16(af[fm][1], bfr[fn][1], acc[fm][fn], 0, 0, 0);
      }
    if (t < 3) WRITET((t + 1) & 1)
    __syncthreads();
  }
#undef LOADT
#undef WRITET

  // ---- epilogue ---- C/D: col(o) = lr, row(p) = g4*4 + reg
  float bvv[4];
  #pragma unroll
  for (int fn = 0; fn < 4; ++fn) bvv[fn] = bias[wn * 64 + fn * 16 + lr];

  if (OMODE == 1) {               // cm f32 direct (final output)
    float* outb = (float*)out + (size_t)b * CH * PIX;
    #pragma unroll
    for (int fm = 0; fm < 4; ++fm)
      #pragma unroll
      for (int fn = 0; fn < 4; ++fn) {
        float4 v;
        v.x = acc[fm][fn][0] + bvv[fn]; v.y = acc[fm][fn][1] + bvv[fn];
        v.z = acc[fm][fn][2] + bvv[fn]; v.w = acc[fm][fn][3] + bvv[fn];
        if (RELU) {
          v.x = fmaxf(v.x, 0.f); v.y = fmaxf(v.y, 0.f);
          v.z = fmaxf(v.z, 0.f); v.w = fmaxf(v.w, 0.f);
        }
        *(float4*)(outb + (size_t)(wn * 64 + fn * 16 + lr) * PIX + p0 + wm * 64 + fm * 16 + g4 * 4) = v;
      }
  } else {                        // pm bf16 via LDS bounce [128][272] halves
    ushort* El = (ushort*)smem;
    #pragma unroll
    for (int fm = 0; fm < 4; ++fm)
      #pragma unroll
      for (int fn = 0; fn < 4; ++fn)
        #pragma unroll
        for (int r = 0; r < 4; ++r) {
          const int p = wm * 64 + fm * 16 + g4 * 4 + r;
          float v = acc[fm][fn][r] + bvv[fn];
          if (RELU) v = fmaxf(v, 0.f);
          El[p * 272 + wn * 64 + fn * 16 + lr] = f2bf(v);
        }
    __syncthreads();
    ushort* outb = (ushort*)out + (size_t)b * PIX * CH;
    const int row = tid >> 2, seg = tid & 3;
    #pragma unroll
    for (int j = 0; j < 8; ++j) {
      uint4 v = *(uint4*)(smem + row * 544 + seg * 128 + j * 16);
      *(uint4*)(outb + (size_t)(p0 + row) * CH + seg * 64 + j * 8) = v;
    }
  }
}

// --------------------------------------------------------------------------
// gemm2_k (r4 version) — retained ONLY for the Cout=192 offs+attn GEMM,
// OMODE 2 (pm f32 out), FUSE 0.
// --------------------------------------------------------------------------
template<int FUSE, bool RELU, int OMODE>
__global__ __launch_bounds__(256, 3) void gemm2_k(
    const ushort* __restrict__ in, const ushort* __restrict__ in2,
    const ushort* __restrict__ Wb, const float* __restrict__ bias,
    void* __restrict__ out, int ldo, size_t obstride)
{
  __shared__ __align__(16) char smem[49152];
  const int tid = threadIdx.x;
  const int b = blockIdx.z;
  const int p0 = blockIdx.x * 128;
  const int o0 = blockIdx.y * 64;

  const ushort* inb = in + (size_t)b * PIX * CH;

  const int spr = tid >> 1, skh = tid & 1;
  const ushort* xsrc = inb + (size_t)(p0 + spr) * CH + skh * 32;
  const int xrow = spr * 128, xsw = spr & 7;
  const int swr = tid >> 2, swq = tid & 3;
  const ushort* wsrc = Wb + (size_t)(o0 + swr) * CH + swq * 16;
  const int wrow = swr * 128, wsw = swr & 7;

  const int l = tid & 63, wv = tid >> 6;
  const int lr = l & 15, g4 = l >> 4;

  f32x4 acc[2][4];
  #pragma unroll
  for (int i = 0; i < 2; ++i)
    #pragma unroll
    for (int j = 0; j < 4; ++j) acc[i][j] = (f32x4){0.f, 0.f, 0.f, 0.f};

  uint4 xr[4], wr[2];

#define LOADT(kb)                                                              \
  {                                                                            \
    _Pragma("unroll")                                                          \
    for (int j = 0; j < 4; ++j) xr[j] = *(const uint4*)(xsrc + (kb) + j * 8);  \
    _Pragma("unroll")                                                          \
    for (int j = 0; j < 2; ++j) wr[j] = *(const uint4*)(wsrc + (kb) + j * 8);  \
  }

#define WRITET(buf)                                                            \
  {                                                                            \
    char* xb = smem + (buf) * 16384 + xrow;                                    \
    _Pragma("unroll")                                                          \
    for (int j = 0; j < 4; ++j)                                                \
      *(uint4*)(xb + (((skh * 4 + j) ^ xsw) * 16)) = xr[j];                    \
    char* wbp = smem + 32768 + (buf) * 8192 + wrow;                            \
    _Pragma("unroll")                                                          \
    for (int j = 0; j < 2; ++j)                                                \
      *(uint4*)(wbp + (((swq * 2 + j) ^ wsw) * 16)) = wr[j];                   \
  }

  LOADT(0)
  WRITET(0)
  __syncthreads();

  for (int t = 0; t < 4; ++t) {
    if (t < 3) LOADT((t + 1) * 64)
    const char* XB = smem + (t & 1) * 16384;
    const char* WB = smem + 32768 + (t & 1) * 8192;
    bf16x8 af[2][2], bfr[4][2];
    #pragma unroll
    for (int fm = 0; fm < 2; ++fm) {
      const int p = wv * 32 + fm * 16 + lr;
      #pragma unroll
      for (int kh = 0; kh < 2; ++kh)
        af[fm][kh] = *(const bf16x8*)(XB + p * 128 + (((kh * 4 + g4) ^ (p & 7)) * 16));
    }
    #pragma unroll
    for (int fn = 0; fn < 4; ++fn) {
      const int o = fn * 16 + lr;
      #pragma unroll
      for (int kh = 0; kh < 2; ++kh)
        bfr[fn][kh] = *(const bf16x8*)(WB + o * 128 + (((kh * 4 + g4) ^ (o & 7)) * 16));
    }
    #pragma unroll
    for (int fm = 0; fm < 2; ++fm)
      #pragma unroll
      for (int fn = 0; fn < 4; ++fn) {
        acc[fm][fn] = __builtin_amdgcn_mfma_f32_16x16x32_bf16(af[fm][0], bfr[fn][0], acc[fm][fn], 0, 0, 0);
        acc[fm][fn] = __builtin_amdgcn_mfma_f32_16x16x32_bf16(af[fm][1], bfr[fn][1], acc[fm][fn], 0, 0, 0);
      }
    if (t < 3) WRITET((t + 1) & 1)
    __syncthreads();
  }
#undef LOADT
#undef WRITET

  float bvv[4];
  #pragma unroll
  for (int fn = 0; fn < 4; ++fn) bvv[fn] = bias[o0 + fn * 16 + lr];

  {                               // OMODE 2: pm f32 via LDS bounce
    float* El = (float*)smem;     // [128][68] f32, pitch 272B
    #pragma unroll
    for (int fm = 0; fm < 2; ++fm)
      #pragma unroll
      for (int fn = 0; fn < 4; ++fn)
        #pragma unroll
        for (int r = 0; r < 4; ++r) {
          const int p = wv * 32 + fm * 16 + g4 * 4 + r;
          float v = acc[fm][fn][r] + bvv[fn];
          if (RELU) v = fmaxf(v, 0.f);
          El[p * 68 + fn * 16 + lr] = v;
        }
    __syncthreads();
    float* outb = (float*)out + (size_t)b * obstride;
    const int row = tid >> 1, hh = tid & 1;
    #pragma unroll
    for (int j = 0; j < 8; ++j) {
      float4 v = *(float4*)(smem + row * 272 + hh * 128 + j * 16);
      *(float4*)(outb + (size_t)(p0 + row) * ldo + o0 + hh * 32 + j * 4) = v;
    }
  }
}

// --------------------------------------------------------------------------
// Fused MSDA, VGPR-dieted: thread per (pixel, head, 16-dim half).
// value pm bf16 [B][P][256]; sa sample-major f32 [B][P][192]; out pm bf16.
// --------------------------------------------------------------------------
__global__ __launch_bounds__(256, 4) void msda_k(
    const ushort* __restrict__ value, const float* __restrict__ sa,
    ushort* __restrict__ out)
{
  const int t = blockIdx.x * 256 + threadIdx.x;   // B*P*16
  const int dh = t & 1;
  const int h = (t >> 1) & 7;
  const int pg = t >> 4;
  const int b = pg >> 14;
  const int p = pg & (PIX - 1);
  const int px = p & 127, py = p >> 7;

  const ushort* vb = value + (size_t)b * PIX * CH;
  const float* sp = sa + (size_t)pg * 192;

  float4 la = *(const float4*)(sp + 128 + h * 8);
  float4 lb = *(const float4*)(sp + 128 + h * 8 + 4);
  float lg[8] = {la.x, la.y, la.z, la.w, lb.x, lb.y, lb.z, lb.w};
  float m = lg[0];
  #pragma unroll
  for (int i = 1; i < 8; ++i) m = fmaxf(m, lg[i]);
  float s = 0.f;
  #pragma unroll
  for (int i = 0; i < 8; ++i) { lg[i] = __expf(lg[i] - m); s += lg[i]; }
  const float inv = 1.f / s;

  float acc[16];
  #pragma unroll
  for (int i = 0; i < 16; ++i) acc[i] = 0.f;

  #pragma unroll 2
  for (int pt = 0; pt < 8; ++pt) {
    const float2 off = *(const float2*)(sp + h * 16 + pt * 2);
    const float aw = lg[pt] * inv;
    const float ix = px + off.x, iy = py + off.y;   // grid_sample -0.5 cancels
    const float xf = floorf(ix), yf = floorf(iy);
    const float fx = ix - xf, fy = iy - yf;
    const int x0 = (int)xf, y0 = (int)yf;
    #pragma unroll
    for (int cr = 0; cr < 4; ++cr) {
      const int dx = cr & 1, dy = cr >> 1;
      const int xx = x0 + dx, yy = y0 + dy;
      const float wx = dx ? fx : (1.f - fx);
      const float wy = dy ? fy : (1.f - fy);
      const bool valid = ((unsigned)xx < 128u) & ((unsigned)yy < 128u);
      float w = valid ? (wx * wy * aw) : 0.f;
      const int xc = min(max(xx, 0), 127), yc = min(max(yy, 0), 127);
      const ushort* vr = vb + ((size_t)(yc * 128 + xc) * CH + h * 32 + dh * 16);
      uint4 q0 = *(const uint4*)vr;
      uint4 q1 = *(const uint4*)(vr + 8);
      const unsigned* qw0 = (const unsigned*)&q0;
      const unsigned* qw1 = (const unsigned*)&q1;
      #pragma unroll
      for (int ww = 0; ww < 4; ++ww) {
        acc[2 * ww + 0] = fmaf(w, bfl(qw0[ww]), acc[2 * ww + 0]);
        acc[2 * ww + 1] = fmaf(w, bfh(qw0[ww]), acc[2 * ww + 1]);
        acc[8 + 2 * ww + 0] = fmaf(w, bfl(qw1[ww]), acc[8 + 2 * ww + 0]);
        acc[8 + 2 * ww + 1] = fmaf(w, bfh(qw1[ww]), acc[8 + 2 * ww + 1]);
      }
    }
  }
  unsigned r[8];
  #pragma unroll
  for (int k = 0; k < 8; ++k)
    r[k] = (unsigned)f2bf(acc[2 * k]) | ((unsigned)f2bf(acc[2 * k + 1]) << 16);
  ushort* dst = out + (size_t)pg * CH + h * 32 + dh * 16;
  *(uint4*)dst = *(uint4*)&r[0];
  *(uint4*)(dst + 8) = *(uint4*)&r[4];
}

extern "C" void kernel_launch(void* const* d_in, const int* in_sizes, int n_in,
                              void* d_out, int out_size, void* d_ws, size_t ws_size,
                              hipStream_t stream)
{
  const float* xt     = (const float*)d_in[0];
  const float* xt_1   = (const float*)d_in[1];
  const float* W_in1  = (const float*)d_in[2];
  const float* b_in1  = (const float*)d_in[3];
  const float* W_in2  = (const float*)d_in[4];
  const float* b_in2  = (const float*)d_in[5];
  const float* Wv     = (const float*)d_in[6];
  const float* bv     = (const float*)d_in[7];
  const float* Ws     = (const float*)d_in[8];
  const float* bs_off = (const float*)d_in[9];
  const float* Wa     = (const float*)d_in[10];
  const float* ba     = (const float*)d_in[11];
  const float* Wo     = (const float*)d_in[12];
  const float* bo     = (const float*)d_in[13];
  const float* Wt1    = (const float*)d_in[14];
  const float* bt1    = (const float*)d_in[15];
  const float* Wt2    = (const float*)d_in[16];
  const float* bt2    = (const float*)d_in[17];
  const float* Wout   = (const float*)d_in[18];
  const float* bout   = (const float*)d_in[19];

  char* ws = (char*)d_ws;
  const size_t SLOT = (size_t)BATCH * PIX * CH * 2;          // 16.78 MB
  const size_t SAB  = (size_t)BATCH * PIX * 192 * 4;         // 25.17 MB
  ushort* s0 = (ushort*)(ws + 0 * SLOT);   // xt_pm  -> xt_star
  ushort* s1 = (ushort*)(ws + 1 * SLOT);   // xt1_pm -> h1
  ushort* s2 = (ushort*)(ws + 2 * SLOT);   // x1 (live to end)
  ushort* s3 = (ushort*)(ws + 3 * SLOT);   // value  -> tg
  ushort* s4 = (ushort*)(ws + 4 * SLOT);   // msda_out
  float*  sa = (float*)(ws + 5 * SLOT);    // [B][P][192] offs+attn
  char* wbase = ws + 5 * SLOT + SAB;
  ushort* wb  = (ushort*)wbase;            // 1472x256 bf16
  ushort* wvp = (ushort*)(wbase + (size_t)1472 * 256 * 2);   // 256x256 bf16
  float* bsa  = (float*)(wbase + (size_t)1472 * 256 * 2 + (size_t)256 * 256 * 2);
  float* bvp  = bsa + 192;

  ushort* wb_in1 = wb;
  ushort* wb_o   = wb + 65536;
  ushort* wb_t1  = wb + 131072;
  ushort* wb_t2  = wb + 196608;
  ushort* wb_out = wb + 262144;
  ushort* wb_sa  = wb + 327680;            // 192 rows: Ws then Wa

  dim3 blk(256);
  dim3 blk5(512);
  dim3 gT(PIX / 32, CH / 32, BATCH);
  dim3 g3(PIX / 128, 1, BATCH);            // gemm3: 256 blocks
  dim3 gS(PIX / 128, 3, BATCH);            // gemm2 Cout=192

  wprep_k<<<1473, blk, 0, stream>>>(W_in1, Wo, Wt1, Wt2, Wout, Ws, Wa, bs_off, ba, wb, bsa);
  wvcomp_k<<<256, blk, 0, stream>>>(Wv, W_in2, b_in2, bv, wvp, bvp);
  tconv_k<<<gT, blk, 0, stream>>>(xt, s0);
  tconv_k<<<gT, blk, 0, stream>>>(xt_1, s1);

  gemm3_k<0, false, 0><<<g3, blk5, 0, stream>>>(s0, nullptr, wb_in1, b_in1, s2);   // x1
  gemm3_k<0, false, 0><<<g3, blk5, 0, stream>>>(s1, nullptr, wvp, bvp, s3);        // value
  gemm2_k<0, false, 2><<<gS, blk, 0, stream>>>(s2, nullptr, wb_sa, bsa, sa, 192, (size_t)PIX * 192); // offs+attn
  msda_k<<<dim3((BATCH * PIX * 16) / 256), blk, 0, stream>>>(s3, sa, s4);
  gemm3_k<0, false, 0><<<g3, blk5, 0, stream>>>(s4, nullptr, wb_o, bo, s0);        // xt_star
  gemm3_k<1, true , 0><<<g3, blk5, 0, stream>>>(s0, s2, wb_t1, bt1, s1);           // h1
  gemm3_k<0, false, 0><<<g3, blk5, 0, stream>>>(s1, nullptr, wb_t2, bt2, s3);      // tg
  gemm3_k<2, true , 1><<<g3, blk5, 0, stream>>>(s3, s2, wb_out, bout, d_out);      // out
}